// Round 7
// baseline (240.840 us; speedup 1.0000x reference)
//
#include <hip/hip_runtime.h>

typedef unsigned short u16;
typedef __bf16 bf16x8 __attribute__((ext_vector_type(8)));
typedef float f32x4 __attribute__((ext_vector_type(4)));
typedef unsigned short u16x8 __attribute__((ext_vector_type(8)));

#define F_FACES 65536
#define N_FACES 131072
#define C_CH 128
// ws layout (bytes):
//   [0,256)        zeropage (zeros; masked-gather target)
//   [256,3328)     W2 folded fp32  [b][o][i]  (768 floats)
//   [5376,595200)  W1 folded bf16, FRAGMENT layout [b][k][chunk16][o128][j8]
//   [595200, +16777216)  const bf16 copy [F][C]  (ends at 17372416)
//   [17372416, +3145728) Y table fp32 [n][b2*3+o]  (131072 x 6; total 20.5MB)
#define WS_W2F 256
#define WS_W1 5376
#define WS_CONST 595200
#define WS_Y 17372416
#define XELEMS 16777216  // N_FACES*128

__device__ inline u16 f2bf(float f) {
    unsigned u = __builtin_bit_cast(unsigned, f);
    unsigned r = (u + 0x7fffu + ((u >> 16) & 1u)) >> 16;
    return (u16)r;
}

__device__ inline void gl_lds16(const void* g, void* l) {
    __builtin_amdgcn_global_load_lds(
        (const __attribute__((address_space(1))) void*)g,
        (__attribute__((address_space(3))) void*)l, 16, 0, 0);
}

// nontemporal 16B load via ext-vector (HIP float4 is a struct -> builtin rejects it)
__device__ inline f32x4 nt_load4(const float* p) {
    return __builtin_nontemporal_load((const f32x4*)p);
}

// ---------------- kernel 0: fused {W1 styles+demod+fold | W2 styles+fold | const cvt}
// blocks [0,256): per-(b,o): compute styles1[b][:] in-block, demod, fold W1 fragments
// block 256: compute styles2 in-block, W2 fold + zeropage
// blocks [257,4353): fp32->bf16 const copy (nontemporal reads -- read-once stream)
__global__ __launch_bounds__(256) void k0_all(
    const float* __restrict__ wsv, const float* __restrict__ a1W, const float* __restrict__ a1b,
    const float* __restrict__ a2W, const float* __restrict__ a2b,
    const float* __restrict__ cst, const float* __restrict__ w1g,
    const float* __restrict__ w2, unsigned char* __restrict__ wsb)
{
    __shared__ float part[2][128];
    __shared__ float s1sh[128];
    __shared__ float red[4];
    int bid = blockIdx.x;
    int tid = threadIdx.x;

    if (bid >= 257) {
        // const fp32 -> bf16 table copy
        u16* dst = (u16*)(wsb + WS_CONST);
        int base = ((bid - 257) * 256 + tid) * 8;
        f32x4 a = nt_load4(cst + base);
        f32x4 c = nt_load4(cst + base + 4);
        u16x8 p;
        p[0] = f2bf(a[0]); p[1] = f2bf(a[1]); p[2] = f2bf(a[2]); p[3] = f2bf(a[3]);
        p[4] = f2bf(c[0]); p[5] = f2bf(c[1]); p[6] = f2bf(c[2]); p[7] = f2bf(c[3]);
        *(u16x8*)(dst + base) = p;
        return;
    }
    const float g512 = 0.04419417382415922f;   // 1/sqrt(512)
    const float g128 = 0.08838834764831845f;   // 1/sqrt(128)
    if (bid < 256) {
        // ---- W1 demod + fold for (b,o); styles1 computed locally ----
        int b = bid >> 7, o = bid & 127;
        int h = tid >> 7, i = tid & 127;
        {
            const float4* xr = (const float4*)(wsv + (size_t)(b * 2 + 0) * 512) + h * 64;
            const float4* ar = (const float4*)(a1W + (size_t)i * 512) + h * 64;
            float p = 0.f;
#pragma unroll 8
            for (int j = 0; j < 64; ++j) {
                float4 w4 = ar[j], x4 = xr[j];
                p += w4.x * x4.x + w4.y * x4.y + w4.z * x4.z + w4.w * x4.w;
            }
            part[h][i] = p;
        }
        __syncthreads();
        if (tid < 128) s1sh[tid] = (part[0][tid] + part[1][tid]) * g512 + a1b[tid];
        __syncthreads();
        float sum = 0.f;
        for (int e = tid; e < 1152; e += 256) {
            int ii = e / 9;
            float w = w1g[(size_t)o * 1152 + e] * s1sh[ii];
            sum += w * w;
        }
        int wv = tid >> 6, lane = tid & 63;
#pragma unroll
        for (int d = 1; d < 64; d <<= 1) sum += __shfl_xor(sum, d);
        if (lane == 0) red[wv] = sum;
        __syncthreads();
        float dm = rsqrtf(red[0] + red[1] + red[2] + red[3] + 1e-8f);
        u16* w1out = (u16*)(wsb + WS_W1);
        for (int wd = tid; wd < 576; wd += 256) {
            int k = wd >> 6;
            int ii = (wd & 63) * 2;
            float v0 = w1g[((size_t)o * 128 + ii) * 9 + k] * s1sh[ii] * dm;
            float v1 = w1g[((size_t)o * 128 + ii + 1) * 9 + k] * s1sh[ii + 1] * dm;
            unsigned pack = (unsigned)f2bf(v0) | ((unsigned)f2bf(v1) << 16);
            *(unsigned*)&w1out[(size_t)((((b * 9 + k) * 16 + (ii >> 3)) * 128 + o) * 8 + (ii & 7))] = pack;
        }
        return;
    }
    // ---- bid == 256: styles2 in-block + zeropage + W2 fold ----
    {
        float* s2sh = &part[0][0];  // reuse 256 floats of LDS
        int b = tid >> 7, i = tid & 127;
        const float4* xr = (const float4*)(wsv + (size_t)(b * 2 + 1) * 512);
        const float4* ar = (const float4*)(a2W + (size_t)i * 512);
        float p = 0.f;
#pragma unroll 8
        for (int j = 0; j < 128; ++j) {
            float4 w4 = ar[j], x4 = xr[j];
            p += w4.x * x4.x + w4.y * x4.y + w4.z * x4.z + w4.w * x4.w;
        }
        s2sh[tid] = (p * g512 + a2b[i]) * g128;
        __syncthreads();
        float* wsf = (float*)wsb;
        if (tid < 64) wsf[tid] = 0.f;
#pragma unroll
        for (int r = 0; r < 3; ++r) {
            int id = tid + r * 256;  // < 768
            int b2 = id / 384;
            int rem = id - b2 * 384;
            int o2 = rem >> 7;
            int ii = rem & 127;
            wsf[WS_W2F / 4 + id] = w2[o2 * 128 + ii] * s2sh[b2 * 128 + ii];
        }
    }
}

// ---------------- kernel 1: gathered GEMM conv1, double-buffered + counted vmcnt ----
// 256 threads (4 waves), 64x128 tile, LDS 2x16KB. R2 structure (proven 67us).
// Epilogue also computes y[n][b2][o] = sum_c x[n][c] * W2f[b2][o][c] for both
// batches (6 dots/row) and stores the 6-float row to the ws Y table -- this is
// conv2's expensive part, done while x is still in registers. k2 becomes a 12B gather.
__global__ __launch_bounds__(256, 5) void k1_conv(
    const int* __restrict__ neigh, const int* __restrict__ ispad,
    const float* __restrict__ noise_c, const float* __restrict__ nstr,
    const float* __restrict__ bias1, const unsigned char* __restrict__ wsb,
    float* __restrict__ out, float* __restrict__ ytab)
{
    __shared__ __align__(16) u16 As[2][64 * 128];  // 2x16KB double buffer, XOR-16 swizzled

    const int tid = threadIdx.x;
    const int wv = tid >> 6, lane = tid & 63;
    const int quad = lane >> 4, l15 = lane & 15;
    const int f0 = blockIdx.x * 64;
    const int b = f0 >> 16;
    const u16* cst = (const u16*)(wsb + WS_CONST);
    const u16* w1ws = (const u16*)(wsb + WS_W1) + (size_t)b * 147456;  // 9*16*128*8
    const char* zp = (const char*)wsb;

    f32x4 acc[4][2] = {};
    int ia[4], ip[4];

    // ---- prologue: idx(0), stage tile0 -> buf0, idx(1) ----
#pragma unroll
    for (int r = 0; r < 4; ++r) {
        int nb = (f0 + (wv * 4 + r) * 4 + quad) * 9 + 0;
        ia[r] = neigh[nb]; ip[r] = ispad[nb];
    }
#pragma unroll
    for (int r = 0; r < 4; ++r) {
        int row = (wv * 4 + r) * 4 + quad;
        bool valid = (ip[r] == 0) && ((unsigned)ia[r] < 131072u);
        const char* src = valid ? (const char*)(cst + ((size_t)(ia[r] & 65535) << 7)) : zp;
        gl_lds16(src + ((l15 ^ (row & 15)) << 4), (char*)(&As[0][0]) + ((wv * 4 + r) << 10));
    }
#pragma unroll
    for (int r = 0; r < 4; ++r) {
        int nb = (f0 + (wv * 4 + r) * 4 + quad) * 9 + 1;
        ia[r] = neigh[nb]; ip[r] = ispad[nb];
    }

#pragma unroll
    for (int k = 0; k < 9; ++k) {
        // B fragments for this k — issued FIRST so consuming them in compute
        // does not FIFO-drain the k+1 gather prefetch.
        bf16x8 bfr[4][2];
#pragma unroll
        for (int s = 0; s < 4; ++s)
#pragma unroll
            for (int nt = 0; nt < 2; ++nt)
                bfr[s][nt] = *reinterpret_cast<const bf16x8*>(
                    w1ws + (((k * 16 + s * 4 + quad) * 128) + wv * 32 + nt * 16 + l15) * 8);
        asm volatile("" ::: "memory");
        __builtin_amdgcn_sched_barrier(0);

        // stage tile k+1 (gather, masked -> zeropage), swizzled source
        if (k < 8) {
#pragma unroll
            for (int r = 0; r < 4; ++r) {
                int row = (wv * 4 + r) * 4 + quad;
                bool valid = (ip[r] == 0) && ((unsigned)ia[r] < 131072u);
                const char* src = valid ? (const char*)(cst + ((size_t)(ia[r] & 65535) << 7)) : zp;
                gl_lds16(src + ((l15 ^ (row & 15)) << 4),
                         (char*)(&As[(k + 1) & 1][0]) + ((wv * 4 + r) << 10));
            }
        }
        // prefetch neighbor indices for tile k+2 (consumed next iteration -> wait is free)
        if (k < 7) {
#pragma unroll
            for (int r = 0; r < 4; ++r) {
                int nb = (f0 + (wv * 4 + r) * 4 + quad) * 9 + (k + 2);
                ia[r] = neigh[nb]; ip[r] = ispad[nb];
            }
        }
        // counted vmcnt: N = ops issued after tile-k's gathers (8 B + 4 gl_lds + 8 idx)
        if (k < 7)       asm volatile("s_waitcnt vmcnt(20)" ::: "memory");
        else if (k == 7) asm volatile("s_waitcnt vmcnt(12)" ::: "memory");
        else             asm volatile("s_waitcnt vmcnt(8)" ::: "memory");
        __builtin_amdgcn_s_barrier();
        __builtin_amdgcn_sched_barrier(0);

        // compute on As[k&1]
        const u16* Ab = &As[k & 1][0];
#pragma unroll
        for (int s = 0; s < 4; ++s) {
            bf16x8 af[4];
#pragma unroll
            for (int mt = 0; mt < 4; ++mt) {
                int face = mt * 16 + l15;
                int chunk = (s * 4 + quad) ^ l15;
                af[mt] = *reinterpret_cast<const bf16x8*>(&Ab[face * 128 + chunk * 8]);
            }
#pragma unroll
            for (int mt = 0; mt < 4; ++mt)
#pragma unroll
                for (int nt = 0; nt < 2; ++nt)
                    acc[mt][nt] = __builtin_amdgcn_mfma_f32_16x16x32_bf16(
                        af[mt], bfr[s][nt], acc[mt][nt], 0, 0, 0);
        }
        asm volatile("s_waitcnt lgkmcnt(0)" ::: "memory");
        __builtin_amdgcn_s_barrier();
        __builtin_amdgcn_sched_barrier(0);
    }

    // ---- epilogue: +noise +bias1, lrelu*sqrt(2), clip, store x; fused conv2 dots ----
    float ns = nstr[0];
    float b1v[2];
    b1v[0] = bias1[wv * 32 + l15];
    b1v[1] = bias1[wv * 32 + 16 + l15];
    const float* w2f = (const float*)(wsb + WS_W2F);
    float w2v[2][3][2];
#pragma unroll
    for (int b2 = 0; b2 < 2; ++b2)
#pragma unroll
        for (int o = 0; o < 3; ++o)
#pragma unroll
            for (int nt = 0; nt < 2; ++nt)
                w2v[b2][o][nt] = w2f[(b2 * 3 + o) * 128 + wv * 32 + nt * 16 + l15];

    float* red = (float*)&As[0][0];  // 64 faces x 4 waves x 6 = 1536 floats (As dead)
#pragma unroll
    for (int mt = 0; mt < 4; ++mt) {
#pragma unroll
        for (int r = 0; r < 4; ++r) {
            int fl = mt * 16 + quad * 4 + r;
            int face = f0 + fl;
            float nz = noise_c[face & 65535] * ns;
            float vv[2];
#pragma unroll
            for (int nt = 0; nt < 2; ++nt) {
                float v = acc[mt][nt][r] + nz + b1v[nt];
                v = (v > 0.f) ? v : 0.2f * v;
                v *= 1.41421356f;
                v = fminf(fmaxf(v, -256.f), 256.f);
                out[(size_t)face * 128 + wv * 32 + nt * 16 + l15] = v;
                vv[nt] = v;
            }
            // 6 partial dots (both batches x 3 outputs), reduce over l15 (intra-quad)
#pragma unroll
            for (int j = 0; j < 6; ++j) {
                float pp = vv[0] * w2v[j / 3][j % 3][0] + vv[1] * w2v[j / 3][j % 3][1];
#pragma unroll
                for (int d = 1; d < 16; d <<= 1) pp += __shfl_xor(pp, d);
                if (l15 == 0) red[fl * 24 + wv * 6 + j] = pp;
            }
        }
    }
    __syncthreads();
    // 384 (face,j) entries but only 256 threads: MUST stride (R5/R6 bug: `if (tid<384)`
    // left faces 43..63 unwritten -> img absmax 7.25)
    for (int t = tid; t < 384; t += 256) {
        int fl = t / 6, j = t - fl * 6;
        float y = red[fl * 24 + j] + red[fl * 24 + 6 + j]
                + red[fl * 24 + 12 + j] + red[fl * 24 + 18 + j];
        ytab[(size_t)(f0 + fl) * 6 + j] = y;
    }
}

// ---------------- kernel 2: img = gather 6-float y row, select batch, +bias, clip ----
// One thread per face; y table is 3MB (L2-resident). Contiguous 12B img writes.
__global__ __launch_bounds__(256) void k2_img(
    const int* __restrict__ neigh, const int* __restrict__ ispad,
    const float* __restrict__ ytab, const float* __restrict__ bias2,
    float* __restrict__ imgout)
{
    int f = blockIdx.x * 256 + threadIdx.x;
    int b = f >> 16;
    int idx = neigh[(size_t)f * 9];
    bool valid = (ispad[(size_t)f * 9] == 0) && ((unsigned)idx < 131072u);
    float v0 = 0.f, v1 = 0.f, v2 = 0.f;
    if (valid) {
        const float* y = ytab + (size_t)idx * 6 + b * 3;
        v0 = y[0]; v1 = y[1]; v2 = y[2];
    }
    v0 = fminf(fmaxf(v0 + bias2[0], -256.f), 256.f);
    v1 = fminf(fmaxf(v1 + bias2[1], -256.f), 256.f);
    v2 = fminf(fmaxf(v2 + bias2[2], -256.f), 256.f);
    imgout[(size_t)f * 3 + 0] = v0;
    imgout[(size_t)f * 3 + 1] = v1;
    imgout[(size_t)f * 3 + 2] = v2;
}

extern "C" void kernel_launch(void* const* d_in, const int* in_sizes, int n_in,
                              void* d_out, int out_size, void* d_ws, size_t ws_size,
                              hipStream_t stream) {
    const int* neigh = (const int*)d_in[0];
    const int* ispad = (const int*)d_in[1];
    const float* wsv = (const float*)d_in[2];
    const float* cst = (const float*)d_in[3];
    const float* a1W = (const float*)d_in[4];
    const float* a1b = (const float*)d_in[5];
    const float* w1g = (const float*)d_in[6];
    const float* noise_c = (const float*)d_in[7];
    const float* nstr = (const float*)d_in[8];
    const float* bias1 = (const float*)d_in[9];
    const float* a2W = (const float*)d_in[10];
    const float* a2b = (const float*)d_in[11];
    const float* w2 = (const float*)d_in[12];
    const float* bias2 = (const float*)d_in[13];
    float* out = (float*)d_out;
    unsigned char* wsb = (unsigned char*)d_ws;
    float* ytab = (float*)(wsb + WS_Y);

    k0_all<<<4353, 256, 0, stream>>>(wsv, a1W, a1b, a2W, a2b, cst, w1g, w2, wsb);
    k1_conv<<<2048, 256, 0, stream>>>(neigh, ispad, noise_c, nstr, bias1, wsb, out, ytab);
    k2_img<<<512, 256, 0, stream>>>(neigh, ispad, ytab, bias2, out + XELEMS);
}

// Round 8
// 220.213 us; speedup vs baseline: 1.0937x; 1.0937x over previous
//
#include <hip/hip_runtime.h>

typedef unsigned short u16;
typedef __bf16 bf16x8 __attribute__((ext_vector_type(8)));
typedef float f32x4 __attribute__((ext_vector_type(4)));
typedef unsigned short u16x8 __attribute__((ext_vector_type(8)));

#define F_FACES 65536
#define N_FACES 131072
#define C_CH 128
// ws layout (bytes):
//   [0,256)        zeropage (zeros; masked-gather target)
//   [256,3328)     W2 folded fp32  [b][o][i]  (768 floats)
//   [5376,595200)  W1 folded bf16, FRAGMENT layout [b][k][chunk16][o128][j8]
//   [595200, +16777216)  const bf16 copy [F][C]  (ends at 17372416)
//   [17372416, +3145728) Y table fp32 [n][b2*3+o]  (131072 x 6; total 20.5MB)
#define WS_W2F 256
#define WS_W1 5376
#define WS_CONST 595200
#define WS_Y 17372416
#define XELEMS 16777216  // N_FACES*128

__device__ inline u16 f2bf(float f) {
    unsigned u = __builtin_bit_cast(unsigned, f);
    unsigned r = (u + 0x7fffu + ((u >> 16) & 1u)) >> 16;
    return (u16)r;
}

__device__ inline void gl_lds16(const void* g, void* l) {
    __builtin_amdgcn_global_load_lds(
        (const __attribute__((address_space(1))) void*)g,
        (__attribute__((address_space(3))) void*)l, 16, 0, 0);
}

// nontemporal 16B load via ext-vector (HIP float4 is a struct -> builtin rejects it)
__device__ inline f32x4 nt_load4(const float* p) {
    return __builtin_nontemporal_load((const f32x4*)p);
}

// VALU-pipe lane-add via DPP (NOT the LDS pipe -- R7's shfl_xor epilogue cost 33us
// of per-CU LDS-pipe serialization). CTRL: 0xB1=quad_perm(xor1), 0x4E=quad_perm(xor2),
// 0x141=row_half_mirror (pairs 8-halves), 0x140=row_mirror (pairs 16-halves).
template <int CTRL>
__device__ inline float dpp_add(float x) {
    int y = __builtin_amdgcn_update_dpp(0, __builtin_bit_cast(int, x), CTRL, 0xF, 0xF, true);
    return x + __builtin_bit_cast(float, y);
}
// full sum over each 16-lane row; result in all 16 lanes
__device__ inline float row16_sum(float x) {
    x = dpp_add<0xB1>(x);
    x = dpp_add<0x4E>(x);
    x = dpp_add<0x141>(x);
    x = dpp_add<0x140>(x);
    return x;
}

// ---------------- kernel 0: fused {W1 styles+demod+fold | W2 styles+fold | const cvt}
// blocks [0,256): per-(b,o): compute styles1[b][:] in-block, demod, fold W1 fragments
// block 256: compute styles2 in-block, W2 fold + zeropage
// blocks [257,4353): fp32->bf16 const copy (nontemporal reads -- read-once stream)
__global__ __launch_bounds__(256) void k0_all(
    const float* __restrict__ wsv, const float* __restrict__ a1W, const float* __restrict__ a1b,
    const float* __restrict__ a2W, const float* __restrict__ a2b,
    const float* __restrict__ cst, const float* __restrict__ w1g,
    const float* __restrict__ w2, unsigned char* __restrict__ wsb)
{
    __shared__ float part[2][128];
    __shared__ float s1sh[128];
    __shared__ float red[4];
    int bid = blockIdx.x;
    int tid = threadIdx.x;

    if (bid >= 257) {
        // const fp32 -> bf16 table copy
        u16* dst = (u16*)(wsb + WS_CONST);
        int base = ((bid - 257) * 256 + tid) * 8;
        f32x4 a = nt_load4(cst + base);
        f32x4 c = nt_load4(cst + base + 4);
        u16x8 p;
        p[0] = f2bf(a[0]); p[1] = f2bf(a[1]); p[2] = f2bf(a[2]); p[3] = f2bf(a[3]);
        p[4] = f2bf(c[0]); p[5] = f2bf(c[1]); p[6] = f2bf(c[2]); p[7] = f2bf(c[3]);
        *(u16x8*)(dst + base) = p;
        return;
    }
    const float g512 = 0.04419417382415922f;   // 1/sqrt(512)
    const float g128 = 0.08838834764831845f;   // 1/sqrt(128)
    if (bid < 256) {
        // ---- W1 demod + fold for (b,o); styles1 computed locally ----
        int b = bid >> 7, o = bid & 127;
        int h = tid >> 7, i = tid & 127;
        {
            const float4* xr = (const float4*)(wsv + (size_t)(b * 2 + 0) * 512) + h * 64;
            const float4* ar = (const float4*)(a1W + (size_t)i * 512) + h * 64;
            float p = 0.f;
#pragma unroll 8
            for (int j = 0; j < 64; ++j) {
                float4 w4 = ar[j], x4 = xr[j];
                p += w4.x * x4.x + w4.y * x4.y + w4.z * x4.z + w4.w * x4.w;
            }
            part[h][i] = p;
        }
        __syncthreads();
        if (tid < 128) s1sh[tid] = (part[0][tid] + part[1][tid]) * g512 + a1b[tid];
        __syncthreads();
        float sum = 0.f;
        for (int e = tid; e < 1152; e += 256) {
            int ii = e / 9;
            float w = w1g[(size_t)o * 1152 + e] * s1sh[ii];
            sum += w * w;
        }
        int wv = tid >> 6, lane = tid & 63;
#pragma unroll
        for (int d = 1; d < 64; d <<= 1) sum += __shfl_xor(sum, d);
        if (lane == 0) red[wv] = sum;
        __syncthreads();
        float dm = rsqrtf(red[0] + red[1] + red[2] + red[3] + 1e-8f);
        u16* w1out = (u16*)(wsb + WS_W1);
        for (int wd = tid; wd < 576; wd += 256) {
            int k = wd >> 6;
            int ii = (wd & 63) * 2;
            float v0 = w1g[((size_t)o * 128 + ii) * 9 + k] * s1sh[ii] * dm;
            float v1 = w1g[((size_t)o * 128 + ii + 1) * 9 + k] * s1sh[ii + 1] * dm;
            unsigned pack = (unsigned)f2bf(v0) | ((unsigned)f2bf(v1) << 16);
            *(unsigned*)&w1out[(size_t)((((b * 9 + k) * 16 + (ii >> 3)) * 128 + o) * 8 + (ii & 7))] = pack;
        }
        return;
    }
    // ---- bid == 256: styles2 in-block + zeropage + W2 fold ----
    {
        float* s2sh = &part[0][0];  // reuse 256 floats of LDS
        int b = tid >> 7, i = tid & 127;
        const float4* xr = (const float4*)(wsv + (size_t)(b * 2 + 1) * 512);
        const float4* ar = (const float4*)(a2W + (size_t)i * 512);
        float p = 0.f;
#pragma unroll 8
        for (int j = 0; j < 128; ++j) {
            float4 w4 = ar[j], x4 = xr[j];
            p += w4.x * x4.x + w4.y * x4.y + w4.z * x4.z + w4.w * x4.w;
        }
        s2sh[tid] = (p * g512 + a2b[i]) * g128;
        __syncthreads();
        float* wsf = (float*)wsb;
        if (tid < 64) wsf[tid] = 0.f;
#pragma unroll
        for (int r = 0; r < 3; ++r) {
            int id = tid + r * 256;  // < 768
            int b2 = id / 384;
            int rem = id - b2 * 384;
            int o2 = rem >> 7;
            int ii = rem & 127;
            wsf[WS_W2F / 4 + id] = w2[o2 * 128 + ii] * s2sh[b2 * 128 + ii];
        }
    }
}

// ---------------- kernel 1: gathered GEMM conv1, double-buffered + counted vmcnt ----
// 256 threads (4 waves), 64x128 tile, LDS 2x16KB. R2 k-loop (proven 67us).
// Epilogue computes the conv2 dots (y table) with DPP row-sums (VALU pipe) +
// 32 ds_write_b128/wave -- replaces R7's 384 shfl/thread LDS-pipe storm (+33us).
__global__ __launch_bounds__(256, 5) void k1_conv(
    const int* __restrict__ neigh, const int* __restrict__ ispad,
    const float* __restrict__ noise_c, const float* __restrict__ nstr,
    const float* __restrict__ bias1, const unsigned char* __restrict__ wsb,
    float* __restrict__ out, float* __restrict__ ytab)
{
    __shared__ __align__(16) u16 As[2][64 * 128];  // 2x16KB double buffer, XOR-16 swizzled

    const int tid = threadIdx.x;
    const int wv = tid >> 6, lane = tid & 63;
    const int quad = lane >> 4, l15 = lane & 15;
    const int f0 = blockIdx.x * 64;
    const int b = f0 >> 16;
    const u16* cst = (const u16*)(wsb + WS_CONST);
    const u16* w1ws = (const u16*)(wsb + WS_W1) + (size_t)b * 147456;  // 9*16*128*8
    const char* zp = (const char*)wsb;

    f32x4 acc[4][2] = {};
    int ia[4], ip[4];

    // ---- prologue: idx(0), stage tile0 -> buf0, idx(1) ----
#pragma unroll
    for (int r = 0; r < 4; ++r) {
        int nb = (f0 + (wv * 4 + r) * 4 + quad) * 9 + 0;
        ia[r] = neigh[nb]; ip[r] = ispad[nb];
    }
#pragma unroll
    for (int r = 0; r < 4; ++r) {
        int row = (wv * 4 + r) * 4 + quad;
        bool valid = (ip[r] == 0) && ((unsigned)ia[r] < 131072u);
        const char* src = valid ? (const char*)(cst + ((size_t)(ia[r] & 65535) << 7)) : zp;
        gl_lds16(src + ((l15 ^ (row & 15)) << 4), (char*)(&As[0][0]) + ((wv * 4 + r) << 10));
    }
#pragma unroll
    for (int r = 0; r < 4; ++r) {
        int nb = (f0 + (wv * 4 + r) * 4 + quad) * 9 + 1;
        ia[r] = neigh[nb]; ip[r] = ispad[nb];
    }

#pragma unroll
    for (int k = 0; k < 9; ++k) {
        // B fragments for this k — issued FIRST so consuming them in compute
        // does not FIFO-drain the k+1 gather prefetch.
        bf16x8 bfr[4][2];
#pragma unroll
        for (int s = 0; s < 4; ++s)
#pragma unroll
            for (int nt = 0; nt < 2; ++nt)
                bfr[s][nt] = *reinterpret_cast<const bf16x8*>(
                    w1ws + (((k * 16 + s * 4 + quad) * 128) + wv * 32 + nt * 16 + l15) * 8);
        asm volatile("" ::: "memory");
        __builtin_amdgcn_sched_barrier(0);

        // stage tile k+1 (gather, masked -> zeropage), swizzled source
        if (k < 8) {
#pragma unroll
            for (int r = 0; r < 4; ++r) {
                int row = (wv * 4 + r) * 4 + quad;
                bool valid = (ip[r] == 0) && ((unsigned)ia[r] < 131072u);
                const char* src = valid ? (const char*)(cst + ((size_t)(ia[r] & 65535) << 7)) : zp;
                gl_lds16(src + ((l15 ^ (row & 15)) << 4),
                         (char*)(&As[(k + 1) & 1][0]) + ((wv * 4 + r) << 10));
            }
        }
        // prefetch neighbor indices for tile k+2 (consumed next iteration -> wait is free)
        if (k < 7) {
#pragma unroll
            for (int r = 0; r < 4; ++r) {
                int nb = (f0 + (wv * 4 + r) * 4 + quad) * 9 + (k + 2);
                ia[r] = neigh[nb]; ip[r] = ispad[nb];
            }
        }
        // counted vmcnt: N = ops issued after tile-k's gathers (8 B + 4 gl_lds + 8 idx)
        if (k < 7)       asm volatile("s_waitcnt vmcnt(20)" ::: "memory");
        else if (k == 7) asm volatile("s_waitcnt vmcnt(12)" ::: "memory");
        else             asm volatile("s_waitcnt vmcnt(8)" ::: "memory");
        __builtin_amdgcn_s_barrier();
        __builtin_amdgcn_sched_barrier(0);

        // compute on As[k&1]
        const u16* Ab = &As[k & 1][0];
#pragma unroll
        for (int s = 0; s < 4; ++s) {
            bf16x8 af[4];
#pragma unroll
            for (int mt = 0; mt < 4; ++mt) {
                int face = mt * 16 + l15;
                int chunk = (s * 4 + quad) ^ l15;
                af[mt] = *reinterpret_cast<const bf16x8*>(&Ab[face * 128 + chunk * 8]);
            }
#pragma unroll
            for (int mt = 0; mt < 4; ++mt)
#pragma unroll
                for (int nt = 0; nt < 2; ++nt)
                    acc[mt][nt] = __builtin_amdgcn_mfma_f32_16x16x32_bf16(
                        af[mt], bfr[s][nt], acc[mt][nt], 0, 0, 0);
        }
        asm volatile("s_waitcnt lgkmcnt(0)" ::: "memory");
        __builtin_amdgcn_s_barrier();
        __builtin_amdgcn_sched_barrier(0);
    }

    // ---- epilogue: +noise +bias1, lrelu*sqrt(2), clip, store x; fused conv2 dots ----
    float ns = nstr[0];
    float b1v[2];
    b1v[0] = bias1[wv * 32 + l15];
    b1v[1] = bias1[wv * 32 + 16 + l15];
    const float* w2f = (const float*)(wsb + WS_W2F);
    float w2v[6][2];
#pragma unroll
    for (int j = 0; j < 6; ++j)
#pragma unroll
        for (int nt = 0; nt < 2; ++nt)
            w2v[j][nt] = w2f[j * 128 + wv * 32 + nt * 16 + l15];

    // red scratch: [fl][wv][12] floats = 12KB (As is dead; barrier above drained reads)
    float* red = (float*)&As[0][0];
#pragma unroll
    for (int mt = 0; mt < 4; ++mt) {
#pragma unroll
        for (int r = 0; r < 4; ++r) {
            int fl = mt * 16 + quad * 4 + r;
            int face = f0 + fl;
            float nz = noise_c[face & 65535] * ns;
            float vv[2];
#pragma unroll
            for (int nt = 0; nt < 2; ++nt) {
                float v = acc[mt][nt][r] + nz + b1v[nt];
                v = (v > 0.f) ? v : 0.2f * v;
                v *= 1.41421356f;
                v = fminf(fmaxf(v, -256.f), 256.f);
                out[(size_t)face * 128 + wv * 32 + nt * 16 + l15] = v;
                vv[nt] = v;
            }
            // 6 dots over this wave's 32 channels: 2 FMA + 4 DPP-adds each (VALU only)
            f32x4 pa, pb;
#pragma unroll
            for (int j = 0; j < 6; ++j) {
                float pp = vv[0] * w2v[j][0] + vv[1] * w2v[j][1];
                pp = row16_sum(pp);   // sum over the 16 channel-lanes of this row
                if (j < 4) pa[j] = pp; else pb[j - 4] = pp;
            }
            pb[2] = 0.f; pb[3] = 0.f;
            if (l15 == 0) {
                float* dst = &red[(fl * 4 + wv) * 12];
                *(f32x4*)(dst) = pa;
                *(f32x4*)(dst + 4) = pb;
            }
        }
    }
    __syncthreads();
    // 384 (face,j) entries, 256 threads: strided loop (R5/R6 bug: `if` dropped 128)
    for (int t = tid; t < 384; t += 256) {
        int fl = t / 6, j = t - fl * 6;
        const float* rp = &red[fl * 48 + j];
        float y = rp[0] + rp[12] + rp[24] + rp[36];
        ytab[(size_t)(f0 + fl) * 6 + j] = y;
    }
}

// ---------------- kernel 2: img = gather 6-float y row, select batch, +bias, clip ----
// One thread per face; y table is 3MB (L2-resident). Contiguous 12B img writes.
__global__ __launch_bounds__(256) void k2_img(
    const int* __restrict__ neigh, const int* __restrict__ ispad,
    const float* __restrict__ ytab, const float* __restrict__ bias2,
    float* __restrict__ imgout)
{
    int f = blockIdx.x * 256 + threadIdx.x;
    int b = f >> 16;
    int idx = neigh[(size_t)f * 9];
    bool valid = (ispad[(size_t)f * 9] == 0) && ((unsigned)idx < 131072u);
    float v0 = 0.f, v1 = 0.f, v2 = 0.f;
    if (valid) {
        const float* y = ytab + (size_t)idx * 6 + b * 3;
        v0 = y[0]; v1 = y[1]; v2 = y[2];
    }
    v0 = fminf(fmaxf(v0 + bias2[0], -256.f), 256.f);
    v1 = fminf(fmaxf(v1 + bias2[1], -256.f), 256.f);
    v2 = fminf(fmaxf(v2 + bias2[2], -256.f), 256.f);
    imgout[(size_t)f * 3 + 0] = v0;
    imgout[(size_t)f * 3 + 1] = v1;
    imgout[(size_t)f * 3 + 2] = v2;
}

extern "C" void kernel_launch(void* const* d_in, const int* in_sizes, int n_in,
                              void* d_out, int out_size, void* d_ws, size_t ws_size,
                              hipStream_t stream) {
    const int* neigh = (const int*)d_in[0];
    const int* ispad = (const int*)d_in[1];
    const float* wsv = (const float*)d_in[2];
    const float* cst = (const float*)d_in[3];
    const float* a1W = (const float*)d_in[4];
    const float* a1b = (const float*)d_in[5];
    const float* w1g = (const float*)d_in[6];
    const float* noise_c = (const float*)d_in[7];
    const float* nstr = (const float*)d_in[8];
    const float* bias1 = (const float*)d_in[9];
    const float* a2W = (const float*)d_in[10];
    const float* a2b = (const float*)d_in[11];
    const float* w2 = (const float*)d_in[12];
    const float* bias2 = (const float*)d_in[13];
    float* out = (float*)d_out;
    unsigned char* wsb = (unsigned char*)d_ws;
    float* ytab = (float*)(wsb + WS_Y);

    k0_all<<<4353, 256, 0, stream>>>(wsv, a1W, a1b, a2W, a2b, cst, w1g, w2, wsb);
    k1_conv<<<2048, 256, 0, stream>>>(neigh, ispad, noise_c, nstr, bias1, wsb, out, ytab);
    k2_img<<<512, 256, 0, stream>>>(neigh, ispad, ytab, bias2, out + XELEMS);
}

// Round 10
// 196.937 us; speedup vs baseline: 1.2229x; 1.1182x over previous
//
#include <hip/hip_runtime.h>

typedef unsigned short u16;
typedef __bf16 bf16x8 __attribute__((ext_vector_type(8)));
typedef float f32x4 __attribute__((ext_vector_type(4)));
typedef unsigned short u16x8 __attribute__((ext_vector_type(8)));

#define F_FACES 65536
#define N_FACES 131072
#define C_CH 128
// ws layout (bytes):
//   [0,256)        zeropage (zeros; masked-gather target)
//   [256,3328)     W2 folded fp32  [b][o][i]  (768 floats)
//   [3328,4352)    styles1 fp32    [b][i]     (256 floats)
//   [4352,5376)    styles2 fp32    [b][i]     (256 floats)
//   [5376,595200)  W1 folded bf16, FRAGMENT layout [b][k][chunk16][o128][j8]
//   [595200, +16777216)  const bf16 copy [F][C]  (ends at 17372416)
//   [17372416, +3145728) Y table fp32 [n][b2*3+o]  (131072 x 6; total 20.5MB)
#define WS_W2F 256
#define WS_S1 3328
#define WS_S2 4352
#define WS_W1 5376
#define WS_CONST 595200
#define WS_Y 17372416
#define XELEMS 16777216  // N_FACES*128

__device__ inline u16 f2bf(float f) {
    unsigned u = __builtin_bit_cast(unsigned, f);
    unsigned r = (u + 0x7fffu + ((u >> 16) & 1u)) >> 16;
    return (u16)r;
}

__device__ inline void gl_lds16(const void* g, void* l) {
    __builtin_amdgcn_global_load_lds(
        (const __attribute__((address_space(1))) void*)g,
        (__attribute__((address_space(3))) void*)l, 16, 0, 0);
}

// VALU-pipe lane-add via DPP (NOT the LDS pipe -- R7's shfl_xor epilogue cost 33us
// of per-CU LDS-pipe serialization). CTRL: 0xB1=quad_perm(xor1), 0x4E=quad_perm(xor2),
// 0x141=row_half_mirror, 0x140=row_mirror.
template <int CTRL>
__device__ inline float dpp_add(float x) {
    int y = __builtin_amdgcn_update_dpp(0, __builtin_bit_cast(int, x), CTRL, 0xF, 0xF, true);
    return x + __builtin_bit_cast(float, y);
}
// full sum over each 16-lane row; result in all 16 lanes
__device__ inline float row16_sum(float x) {
    x = dpp_add<0xB1>(x);
    x = dpp_add<0x4E>(x);
    x = dpp_add<0x141>(x);
    x = dpp_add<0x140>(x);
    return x;
}

// ---------------- kernel 0a: styles1+styles2, one wave per 512-dot (R2-proven) ----
__global__ __launch_bounds__(256) void k0a_styles(
    const float* __restrict__ wsv, const float* __restrict__ a1W, const float* __restrict__ a1b,
    const float* __restrict__ a2W, const float* __restrict__ a2b, unsigned char* __restrict__ wsb)
{
    int wv = threadIdx.x >> 6, lane = threadIdx.x & 63;
    int c = blockIdx.x * 4 + wv;
    int which = c >> 8, rem = c & 255, b = rem >> 7, o = rem & 127;
    const float* W = (which ? a2W : a1W) + o * 512 + lane * 8;
    const float* x = wsv + (b * 2 + which) * 512 + lane * 8;
    float4 wa = *(const float4*)(W);
    float4 wb = *(const float4*)(W + 4);
    float4 xa = *(const float4*)(x);
    float4 xb = *(const float4*)(x + 4);
    float s = wa.x * xa.x + wa.y * xa.y + wa.z * xa.z + wa.w * xa.w
            + wb.x * xb.x + wb.y * xb.y + wb.z * xb.z + wb.w * xb.w;
#pragma unroll
    for (int d = 1; d < 64; d <<= 1) s += __shfl_xor(s, d);
    if (lane == 0) {
        const float g512 = 0.04419417382415922f;   // 1/sqrt(512)
        const float g128 = 0.08838834764831845f;   // 1/sqrt(128)
        float* wsf = (float*)wsb;
        if (which == 0) {
            wsf[WS_S1 / 4 + b * 128 + o] = s * g512 + a1b[o];
        } else {
            wsf[WS_S2 / 4 + b * 128 + o] = (s * g512 + a2b[o]) * g128;
        }
    }
}

// ---------------- kernel 0f: fused {W1 demod+fold | W2 fold+zeropage | const cvt} ----
// R2-proven version: fold blocks read styles from ws; cvt uses PLAIN loads (the R3
// merged-styles + nt-load variant cost ~37us of k0 time -- reverted).
// blocks [0,256): per-(b,o) demod + fold of W1 fragments (dispatched first)
// block 256: zeropage + W2 fold
// blocks [257,4353): fp32->bf16 const copy
__global__ __launch_bounds__(256) void k0f_fused(
    const float* __restrict__ cst, const float* __restrict__ w1g,
    const float* __restrict__ w2, unsigned char* __restrict__ wsb)
{
    __shared__ float red[4];
    int bid = blockIdx.x;
    int tid = threadIdx.x;

    if (bid >= 257) {
        u16* dst = (u16*)(wsb + WS_CONST);
        int base = ((bid - 257) * 256 + tid) * 8;
        float4 a = *(const float4*)(cst + base);
        float4 c = *(const float4*)(cst + base + 4);
        u16x8 p;
        p[0] = f2bf(a.x); p[1] = f2bf(a.y); p[2] = f2bf(a.z); p[3] = f2bf(a.w);
        p[4] = f2bf(c.x); p[5] = f2bf(c.y); p[6] = f2bf(c.z); p[7] = f2bf(c.w);
        *(u16x8*)(dst + base) = p;
        return;
    }
    if (bid < 256) {
        int b = bid >> 7, o = bid & 127;
        const float* s1 = (const float*)(wsb + WS_S1) + b * 128;
        float sum = 0.f;
        for (int e = tid; e < 1152; e += 256) {
            int i = e / 9;
            float w = w1g[(size_t)o * 1152 + e] * s1[i];
            sum += w * w;
        }
        int wv = tid >> 6, lane = tid & 63;
#pragma unroll
        for (int d = 1; d < 64; d <<= 1) sum += __shfl_xor(sum, d);
        if (lane == 0) red[wv] = sum;
        __syncthreads();
        float dm = rsqrtf(red[0] + red[1] + red[2] + red[3] + 1e-8f);
        u16* w1out = (u16*)(wsb + WS_W1);
        for (int wd = tid; wd < 576; wd += 256) {
            int k = wd >> 6;
            int ii = (wd & 63) * 2;
            float v0 = w1g[((size_t)o * 128 + ii) * 9 + k] * s1[ii] * dm;
            float v1 = w1g[((size_t)o * 128 + ii + 1) * 9 + k] * s1[ii + 1] * dm;
            unsigned pack = (unsigned)f2bf(v0) | ((unsigned)f2bf(v1) << 16);
            *(unsigned*)&w1out[(size_t)((((b * 9 + k) * 16 + (ii >> 3)) * 128 + o) * 8 + (ii & 7))] = pack;
        }
        return;
    }
    // bid == 256: zeropage + W2 fold
    float* wsf = (float*)wsb;
    if (tid < 64) wsf[tid] = 0.f;
#pragma unroll
    for (int r = 0; r < 3; ++r) {
        int id = tid + r * 256;  // < 768
        int b2 = id / 384;
        int rem = id - b2 * 384;
        int o2 = rem >> 7;
        int i = rem & 127;
        wsf[WS_W2F / 4 + id] = w2[o2 * 128 + i] * wsf[WS_S2 / 4 + b2 * 128 + i];
    }
}

// ---------------- kernel 1: gathered GEMM conv1, double-buffered + counted vmcnt ----
// 256 threads (4 waves), 64x128 tile, LDS 2x16KB. R2 k-loop (proven 67us).
// Epilogue computes the conv2 dots (y table) with DPP row-sums (VALU pipe) +
// 32 ds_write_b128/wave -- R8-proven (77.6us, conflicts 196K).
__global__ __launch_bounds__(256, 5) void k1_conv(
    const int* __restrict__ neigh, const int* __restrict__ ispad,
    const float* __restrict__ noise_c, const float* __restrict__ nstr,
    const float* __restrict__ bias1, const unsigned char* __restrict__ wsb,
    float* __restrict__ out, float* __restrict__ ytab)
{
    __shared__ __align__(16) u16 As[2][64 * 128];  // 2x16KB double buffer, XOR-16 swizzled

    const int tid = threadIdx.x;
    const int wv = tid >> 6, lane = tid & 63;
    const int quad = lane >> 4, l15 = lane & 15;
    const int f0 = blockIdx.x * 64;
    const int b = f0 >> 16;
    const u16* cst = (const u16*)(wsb + WS_CONST);
    const u16* w1ws = (const u16*)(wsb + WS_W1) + (size_t)b * 147456;  // 9*16*128*8
    const char* zp = (const char*)wsb;

    f32x4 acc[4][2] = {};
    int ia[4], ip[4];

    // ---- prologue: idx(0), stage tile0 -> buf0, idx(1) ----
#pragma unroll
    for (int r = 0; r < 4; ++r) {
        int nb = (f0 + (wv * 4 + r) * 4 + quad) * 9 + 0;
        ia[r] = neigh[nb]; ip[r] = ispad[nb];
    }
#pragma unroll
    for (int r = 0; r < 4; ++r) {
        int row = (wv * 4 + r) * 4 + quad;
        bool valid = (ip[r] == 0) && ((unsigned)ia[r] < 131072u);
        const char* src = valid ? (const char*)(cst + ((size_t)(ia[r] & 65535) << 7)) : zp;
        gl_lds16(src + ((l15 ^ (row & 15)) << 4), (char*)(&As[0][0]) + ((wv * 4 + r) << 10));
    }
#pragma unroll
    for (int r = 0; r < 4; ++r) {
        int nb = (f0 + (wv * 4 + r) * 4 + quad) * 9 + 1;
        ia[r] = neigh[nb]; ip[r] = ispad[nb];
    }

#pragma unroll
    for (int k = 0; k < 9; ++k) {
        // B fragments for this k — issued FIRST so consuming them in compute
        // does not FIFO-drain the k+1 gather prefetch.
        bf16x8 bfr[4][2];
#pragma unroll
        for (int s = 0; s < 4; ++s)
#pragma unroll
            for (int nt = 0; nt < 2; ++nt)
                bfr[s][nt] = *reinterpret_cast<const bf16x8*>(
                    w1ws + (((k * 16 + s * 4 + quad) * 128) + wv * 32 + nt * 16 + l15) * 8);
        asm volatile("" ::: "memory");
        __builtin_amdgcn_sched_barrier(0);

        // stage tile k+1 (gather, masked -> zeropage), swizzled source
        if (k < 8) {
#pragma unroll
            for (int r = 0; r < 4; ++r) {
                int row = (wv * 4 + r) * 4 + quad;
                bool valid = (ip[r] == 0) && ((unsigned)ia[r] < 131072u);
                const char* src = valid ? (const char*)(cst + ((size_t)(ia[r] & 65535) << 7)) : zp;
                gl_lds16(src + ((l15 ^ (row & 15)) << 4),
                         (char*)(&As[(k + 1) & 1][0]) + ((wv * 4 + r) << 10));
            }
        }
        // prefetch neighbor indices for tile k+2 (consumed next iteration -> wait is free)
        if (k < 7) {
#pragma unroll
            for (int r = 0; r < 4; ++r) {
                int nb = (f0 + (wv * 4 + r) * 4 + quad) * 9 + (k + 2);
                ia[r] = neigh[nb]; ip[r] = ispad[nb];
            }
        }
        // counted vmcnt: N = ops issued after tile-k's gathers (8 B + 4 gl_lds + 8 idx)
        if (k < 7)       asm volatile("s_waitcnt vmcnt(20)" ::: "memory");
        else if (k == 7) asm volatile("s_waitcnt vmcnt(12)" ::: "memory");
        else             asm volatile("s_waitcnt vmcnt(8)" ::: "memory");
        __builtin_amdgcn_s_barrier();
        __builtin_amdgcn_sched_barrier(0);

        // compute on As[k&1]
        const u16* Ab = &As[k & 1][0];
#pragma unroll
        for (int s = 0; s < 4; ++s) {
            bf16x8 af[4];
#pragma unroll
            for (int mt = 0; mt < 4; ++mt) {
                int face = mt * 16 + l15;
                int chunk = (s * 4 + quad) ^ l15;
                af[mt] = *reinterpret_cast<const bf16x8*>(&Ab[face * 128 + chunk * 8]);
            }
#pragma unroll
            for (int mt = 0; mt < 4; ++mt)
#pragma unroll
                for (int nt = 0; nt < 2; ++nt)
                    acc[mt][nt] = __builtin_amdgcn_mfma_f32_16x16x32_bf16(
                        af[mt], bfr[s][nt], acc[mt][nt], 0, 0, 0);
        }
        asm volatile("s_waitcnt lgkmcnt(0)" ::: "memory");
        __builtin_amdgcn_s_barrier();
        __builtin_amdgcn_sched_barrier(0);
    }

    // ---- epilogue: +noise +bias1, lrelu*sqrt(2), clip, store x; fused conv2 dots ----
    float ns = nstr[0];
    float b1v[2];
    b1v[0] = bias1[wv * 32 + l15];
    b1v[1] = bias1[wv * 32 + 16 + l15];
    const float* w2f = (const float*)(wsb + WS_W2F);
    float w2v[6][2];
#pragma unroll
    for (int j = 0; j < 6; ++j)
#pragma unroll
        for (int nt = 0; nt < 2; ++nt)
            w2v[j][nt] = w2f[j * 128 + wv * 32 + nt * 16 + l15];

    // red scratch: [fl][wv][12] floats = 12KB (As is dead; barrier above drained reads)
    float* red = (float*)&As[0][0];
#pragma unroll
    for (int mt = 0; mt < 4; ++mt) {
#pragma unroll
        for (int r = 0; r < 4; ++r) {
            int fl = mt * 16 + quad * 4 + r;
            int face = f0 + fl;
            float nz = noise_c[face & 65535] * ns;
            float vv[2];
#pragma unroll
            for (int nt = 0; nt < 2; ++nt) {
                float v = acc[mt][nt][r] + nz + b1v[nt];
                v = (v > 0.f) ? v : 0.2f * v;
                v *= 1.41421356f;
                v = fminf(fmaxf(v, -256.f), 256.f);
                out[(size_t)face * 128 + wv * 32 + nt * 16 + l15] = v;
                vv[nt] = v;
            }
            // 6 dots over this wave's 32 channels: 2 FMA + 4 DPP-adds each (VALU only)
            f32x4 pa, pb;
#pragma unroll
            for (int j = 0; j < 6; ++j) {
                float pp = vv[0] * w2v[j][0] + vv[1] * w2v[j][1];
                pp = row16_sum(pp);   // sum over the 16 channel-lanes of this row
                if (j < 4) pa[j] = pp; else pb[j - 4] = pp;
            }
            pb[2] = 0.f; pb[3] = 0.f;
            if (l15 == 0) {
                float* dst = &red[(fl * 4 + wv) * 12];
                *(f32x4*)(dst) = pa;
                *(f32x4*)(dst + 4) = pb;
            }
        }
    }
    __syncthreads();
    // 384 (face,j) entries, 256 threads: strided loop (R5/R6 bug: `if` dropped 128)
    for (int t = tid; t < 384; t += 256) {
        int fl = t / 6, j = t - fl * 6;
        const float* rp = &red[fl * 48 + j];
        float y = rp[0] + rp[12] + rp[24] + rp[36];
        ytab[(size_t)(f0 + fl) * 6 + j] = y;
    }
}

// ---------------- kernel 2: img = gather 6-float y row, select batch, +bias, clip ----
// One thread per face; y table is 3MB (L2-resident). Contiguous 12B img writes.
__global__ __launch_bounds__(256) void k2_img(
    const int* __restrict__ neigh, const int* __restrict__ ispad,
    const float* __restrict__ ytab, const float* __restrict__ bias2,
    float* __restrict__ imgout)
{
    int f = blockIdx.x * 256 + threadIdx.x;
    int b = f >> 16;
    int idx = neigh[(size_t)f * 9];
    bool valid = (ispad[(size_t)f * 9] == 0) && ((unsigned)idx < 131072u);
    float v0 = 0.f, v1 = 0.f, v2 = 0.f;
    if (valid) {
        const float* y = ytab + (size_t)idx * 6 + b * 3;
        v0 = y[0]; v1 = y[1]; v2 = y[2];
    }
    v0 = fminf(fmaxf(v0 + bias2[0], -256.f), 256.f);
    v1 = fminf(fmaxf(v1 + bias2[1], -256.f), 256.f);
    v2 = fminf(fmaxf(v2 + bias2[2], -256.f), 256.f);
    imgout[(size_t)f * 3 + 0] = v0;
    imgout[(size_t)f * 3 + 1] = v1;
    imgout[(size_t)f * 3 + 2] = v2;
}

extern "C" void kernel_launch(void* const* d_in, const int* in_sizes, int n_in,
                              void* d_out, int out_size, void* d_ws, size_t ws_size,
                              hipStream_t stream) {
    const int* neigh = (const int*)d_in[0];
    const int* ispad = (const int*)d_in[1];
    const float* wsv = (const float*)d_in[2];
    const float* cst = (const float*)d_in[3];
    const float* a1W = (const float*)d_in[4];
    const float* a1b = (const float*)d_in[5];
    const float* w1g = (const float*)d_in[6];
    const float* noise_c = (const float*)d_in[7];
    const float* nstr = (const float*)d_in[8];
    const float* bias1 = (const float*)d_in[9];
    const float* a2W = (const float*)d_in[10];
    const float* a2b = (const float*)d_in[11];
    const float* w2 = (const float*)d_in[12];
    const float* bias2 = (const float*)d_in[13];
    float* out = (float*)d_out;
    unsigned char* wsb = (unsigned char*)d_ws;
    float* ytab = (float*)(wsb + WS_Y);

    k0a_styles<<<128, 256, 0, stream>>>(wsv, a1W, a1b, a2W, a2b, wsb);
    k0f_fused<<<4353, 256, 0, stream>>>(cst, w1g, w2, wsb);
    k1_conv<<<2048, 256, 0, stream>>>(neigh, ispad, noise_c, nstr, bias1, wsb, out, ytab);
    k2_img<<<512, 256, 0, stream>>>(neigh, ispad, ytab, bias2, out + XELEMS);
}